// Round 3
// baseline (395.799 us; speedup 1.0000x reference)
//
#include <hip/hip_runtime.h>

#define H_ 8
#define B_ 4
#define N_ 2048
#define D_ 64
#define EPS_ 0.0009765625f
#define QT 64
#define KT 64

// ---------------------------------------------------------------------------
// Mask canonicalization: padding_mask is jax bool; device buffer may be
// uint8 (1B/elem), int32, or float32. Detect format from first n/4 words
// (safe to read in all layouts) and expand to float 0/1 in d_ws.
// ---------------------------------------------------------------------------
__global__ __launch_bounds__(256) void prep_mask_kernel(const void* __restrict__ min_,
                                                        float* __restrict__ mout, int n) {
    __shared__ int okInt, okFloat;
    const int t = threadIdx.x;
    if (t == 0) { okInt = 1; okFloat = 1; }
    __syncthreads();
    const unsigned int* w = (const unsigned int*)min_;
    const int nw = n / 4;  // safe word count even if buffer is bytes
    int badI = 0, badF = 0;
    for (int i = t; i < nw; i += 256) {
        const unsigned int x = w[i];
        if (x > 1u) badI = 1;
        if (x != 0u && x != 0x3F800000u) badF = 1;
    }
    if (badI) atomicAnd(&okInt, 0);
    if (badF) atomicAnd(&okFloat, 0);
    __syncthreads();
    if (okInt) {
        const int* p = (const int*)min_;
        for (int i = t; i < n; i += 256) mout[i] = p[i] ? 1.0f : 0.0f;
    } else if (okFloat) {
        const float* p = (const float*)min_;
        for (int i = t; i < n; i += 256) mout[i] = (p[i] != 0.0f) ? 1.0f : 0.0f;
    } else {
        const unsigned char* p = (const unsigned char*)min_;
        for (int i = t; i < n; i += 256) mout[i] = p[i] ? 1.0f : 0.0f;
    }
}

// ---------------------------------------------------------------------------
// Ordered compaction of unmasked key indices per batch. One block per b.
// Deterministic (prefix-sum) so timing replays are stable.
// ---------------------------------------------------------------------------
__global__ __launch_bounds__(256) void compact_kernel(const float* __restrict__ maskf,
                                                      int* __restrict__ idx,
                                                      int* __restrict__ cnt) {
    const int b = blockIdx.x;
    const int t = threadIdx.x;
    __shared__ int pre[257];
    const float* m = maskf + b * N_;
    int loc[8];
    int c = 0;
#pragma unroll
    for (int i = 0; i < 8; ++i) {
        loc[i] = (m[t * 8 + i] != 0.0f) ? 1 : 0;
        c += loc[i];
    }
    pre[t + 1] = c;
    __syncthreads();
    if (t == 0) {
        pre[0] = 0;
        for (int i = 1; i <= 256; ++i) pre[i] += pre[i - 1];
        cnt[b] = pre[256];
    }
    __syncthreads();
    int base = pre[t];
    int* ob = idx + b * N_;
#pragma unroll
    for (int i = 0; i < 8; ++i)
        if (loc[i]) ob[base++] = t * 8 + i;
}

// ---------------------------------------------------------------------------
// Flash-style Gaussian-kernel attention, fp32 VALU, compacted keys.
// Block: 64 query rows of one (b,h); 256 threads as 16x16, 4x4 regs each.
// LDS: Q tile + K tile (reused for the score tile W) + V tile, stride-64,
// XOR-swizzled (c4 ^= (row>>2)&7) so all ds_read_b128 are conflict-free.
// Key loop runs over cnt[b] compacted (unmasked) keys only — exact math,
// since masked keys contribute 0 to both denom and PV.
// ---------------------------------------------------------------------------
__global__ __launch_bounds__(256) void hept_attn_kernel(
    const float* __restrict__ Q, const float* __restrict__ K,
    const float* __restrict__ V, const float* __restrict__ maskf,
    const int* __restrict__ idx, const int* __restrict__ cnt,
    float* __restrict__ Out) {
    __shared__ float Qs[QT * D_];
    __shared__ float KWs[KT * D_];   // K tile, then (after barC) the score tile W
    __shared__ float Vs[KT * D_];    // V tile; reused as dpart[16][64] at the end
    __shared__ float q2s[QT];
    __shared__ float k2s[KT];
    __shared__ float mks[KT];        // validity of compacted row (1 real / 0 pad)

    const int t = threadIdx.x;
    const int tr = t >> 4;   // 0..15 -> rows 4*tr..4*tr+3
    const int tc = t & 15;   // 0..15 -> cols 4*tc..4*tc+3
    const int q0 = blockIdx.x * QT;
    const int head = blockIdx.y & 7;
    const int b = blockIdx.y >> 3;

    const size_t plane = (size_t)(B_ * N_) * D_;
    const float* Qp = Q + (size_t)head * plane + (size_t)(b * N_ + q0) * D_;
    const float* Kp = K + (size_t)head * plane + (size_t)(b * N_) * D_;
    const float* Vp = V + (size_t)head * plane + (size_t)(b * N_) * D_;
    float* Op = Out + (size_t)head * plane + (size_t)(b * N_ + q0) * D_;
    const float* mrow = maskf + b * N_;
    const int* idxb = idx + b * N_;
    const int kcnt = cnt[b];
    const int ntile = (kcnt + KT - 1) / KT;

    // ---- stage Q tile (swizzled) ----
    for (int f = t; f < QT * D_ / 4; f += 256) {
        const int r = f >> 4, c4 = f & 15;
        const float4 v = *(const float4*)(Qp + r * D_ + (c4 << 2));
        const int cs = c4 ^ ((r >> 2) & 7);
        *(float4*)&Qs[r * D_ + (cs << 2)] = v;
    }
    __syncthreads();
    if (t < QT) {  // ||q||^2 per row
        float s = 0.f;
        const int sw = (t >> 2) & 7;
#pragma unroll
        for (int i4 = 0; i4 < 16; ++i4) {
            const float4 v = *(const float4*)&Qs[t * D_ + ((i4 ^ sw) << 2)];
            s = fmaf(v.x, v.x, s); s = fmaf(v.y, v.y, s);
            s = fmaf(v.z, v.z, s); s = fmaf(v.w, v.w, s);
        }
        q2s[t] = s;
    }

    float4 accO[4];
#pragma unroll
    for (int a = 0; a < 4; ++a) accO[a] = make_float4(0.f, 0.f, 0.f, 0.f);
    float dsum[4] = {0.f, 0.f, 0.f, 0.f};

    const int swA = tr & 7;  // swizzle key for this thread's Q/W rows (r>>2 == tr)
    const int swB = tc & 7;  // swizzle key for this thread's K rows   (k>>2 == tc)

    for (int kt = 0; kt < ntile; ++kt) {
        const int k0 = kt * KT;
        __syncthreads();  // barA: prev PV reads done (and q2s visible on iter 0)
        for (int f = t; f < KT * D_ / 4; f += 256) {
            const int r = f >> 4, c4 = f & 15;
            const int j = k0 + r;
            const int ki = (j < kcnt) ? idxb[j] : idxb[0];  // clamp pads to a valid row
            const int cs = c4 ^ ((r >> 2) & 7);
            *(float4*)&KWs[r * D_ + (cs << 2)] = *(const float4*)(Kp + (size_t)ki * D_ + (c4 << 2));
            *(float4*)&Vs[r * D_ + (cs << 2)]  = *(const float4*)(Vp + (size_t)ki * D_ + (c4 << 2));
        }
        if (t < KT) mks[t] = (k0 + t < kcnt) ? 1.0f : 0.0f;
        __syncthreads();  // barB: K/V/mks visible

        if (t < KT) {  // ||k||^2 per row (used after barC)
            float s = 0.f;
            const int sw = (t >> 2) & 7;
#pragma unroll
            for (int i4 = 0; i4 < 16; ++i4) {
                const float4 v = *(const float4*)&KWs[t * D_ + ((i4 ^ sw) << 2)];
                s = fmaf(v.x, v.x, s); s = fmaf(v.y, v.y, s);
                s = fmaf(v.z, v.z, s); s = fmaf(v.w, v.w, s);
            }
            k2s[t] = s;
        }

        // ---- QK^T: 4x4 dot-products in registers ----
        float dot[4][4];
#pragma unroll
        for (int a = 0; a < 4; ++a)
#pragma unroll
            for (int c = 0; c < 4; ++c) dot[a][c] = 0.f;
#pragma unroll
        for (int i4 = 0; i4 < 16; ++i4) {
            float4 qv[4], kv[4];
            const int qc = (i4 ^ swA) << 2;
            const int kc = (i4 ^ swB) << 2;
#pragma unroll
            for (int a = 0; a < 4; ++a) qv[a] = *(const float4*)&Qs[(4 * tr + a) * D_ + qc];
#pragma unroll
            for (int c = 0; c < 4; ++c) kv[c] = *(const float4*)&KWs[(4 * tc + c) * D_ + kc];
#pragma unroll
            for (int a = 0; a < 4; ++a)
#pragma unroll
                for (int c = 0; c < 4; ++c) {
                    dot[a][c] = fmaf(qv[a].x, kv[c].x, dot[a][c]);
                    dot[a][c] = fmaf(qv[a].y, kv[c].y, dot[a][c]);
                    dot[a][c] = fmaf(qv[a].z, kv[c].z, dot[a][c]);
                    dot[a][c] = fmaf(qv[a].w, kv[c].w, dot[a][c]);
                }
        }
        __syncthreads();  // barC: all K reads done, k2s visible -> can overwrite KWs

        // ---- w = exp(-0.5*dist)*valid, accumulate denom, store W tile ----
        float4 wrow[4];
#pragma unroll
        for (int a = 0; a < 4; ++a) {
            const float q2 = q2s[4 * tr + a];
            const float w0 = __expf(-0.5f * (q2 + k2s[4 * tc + 0] - 2.f * dot[a][0])) * mks[4 * tc + 0];
            const float w1 = __expf(-0.5f * (q2 + k2s[4 * tc + 1] - 2.f * dot[a][1])) * mks[4 * tc + 1];
            const float w2 = __expf(-0.5f * (q2 + k2s[4 * tc + 2] - 2.f * dot[a][2])) * mks[4 * tc + 2];
            const float w3 = __expf(-0.5f * (q2 + k2s[4 * tc + 3] - 2.f * dot[a][3])) * mks[4 * tc + 3];
            dsum[a] += (w0 + w1) + (w2 + w3);
            wrow[a] = make_float4(w0, w1, w2, w3);
        }
#pragma unroll
        for (int a = 0; a < 4; ++a) {
            const int r = 4 * tr + a;
            *(float4*)&KWs[r * D_ + ((tc ^ swA) << 2)] = wrow[a];
        }
        __syncthreads();  // barD: W tile visible

        // ---- PV: accO[r][4tc..] += W[r][k] * V[k][4tc..] ----
#pragma unroll
        for (int k4 = 0; k4 < 16; ++k4) {
            float4 wv[4], vv[4];
            const int wc = (k4 ^ swA) << 2;
            const int vc = (tc ^ (k4 & 7)) << 2;
#pragma unroll
            for (int a = 0; a < 4; ++a) wv[a] = *(const float4*)&KWs[(4 * tr + a) * D_ + wc];
#pragma unroll
            for (int c = 0; c < 4; ++c) vv[c] = *(const float4*)&Vs[(4 * k4 + c) * D_ + vc];
#pragma unroll
            for (int a = 0; a < 4; ++a) {
                accO[a].x = fmaf(wv[a].x, vv[0].x, accO[a].x);
                accO[a].x = fmaf(wv[a].y, vv[1].x, accO[a].x);
                accO[a].x = fmaf(wv[a].z, vv[2].x, accO[a].x);
                accO[a].x = fmaf(wv[a].w, vv[3].x, accO[a].x);
                accO[a].y = fmaf(wv[a].x, vv[0].y, accO[a].y);
                accO[a].y = fmaf(wv[a].y, vv[1].y, accO[a].y);
                accO[a].y = fmaf(wv[a].z, vv[2].y, accO[a].y);
                accO[a].y = fmaf(wv[a].w, vv[3].y, accO[a].y);
                accO[a].z = fmaf(wv[a].x, vv[0].z, accO[a].z);
                accO[a].z = fmaf(wv[a].y, vv[1].z, accO[a].z);
                accO[a].z = fmaf(wv[a].z, vv[2].z, accO[a].z);
                accO[a].z = fmaf(wv[a].w, vv[3].z, accO[a].z);
                accO[a].w = fmaf(wv[a].x, vv[0].w, accO[a].w);
                accO[a].w = fmaf(wv[a].y, vv[1].w, accO[a].w);
                accO[a].w = fmaf(wv[a].z, vv[2].w, accO[a].w);
                accO[a].w = fmaf(wv[a].w, vv[3].w, accO[a].w);
            }
        }
    }

    // ---- denominator reduction across the 16 tc groups (dpart aliases Vs) ----
    __syncthreads();
    float* dpart = Vs;  // [16][64]
#pragma unroll
    for (int a = 0; a < 4; ++a) dpart[tc * QT + 4 * tr + a] = dsum[a];
    __syncthreads();
#pragma unroll
    for (int a = 0; a < 4; ++a) {
        const int r = 4 * tr + a;
        float den = EPS_;
#pragma unroll
        for (int j = 0; j < 16; ++j) den += dpart[j * QT + r];
        const float mq = mrow[q0 + r];
        const float inv = mq / den;
        const float4 o = make_float4(accO[a].x * inv, accO[a].y * inv,
                                     accO[a].z * inv, accO[a].w * inv);
        *(float4*)(Op + (size_t)r * D_ + (tc << 2)) = o;
    }
}

extern "C" void kernel_launch(void* const* d_in, const int* in_sizes, int n_in,
                              void* d_out, int out_size, void* d_ws, size_t ws_size,
                              hipStream_t stream) {
    (void)n_in; (void)out_size; (void)ws_size;
    const float* Q = (const float*)d_in[0];
    const float* K = (const float*)d_in[1];
    const float* V = (const float*)d_in[2];
    const void* mask = d_in[3];
    const int nmask = in_sizes[3];         // B*N = 8192

    // workspace layout: [0, 8192) floats mask | [8192, 8196) cnt | [8256, 16448) idx
    float* maskf = (float*)d_ws;
    int* cnt = (int*)d_ws + 8192;
    int* idx = (int*)d_ws + 8256;

    prep_mask_kernel<<<1, 256, 0, stream>>>(mask, maskf, nmask);
    compact_kernel<<<B_, 256, 0, stream>>>(maskf, idx, cnt);
    dim3 grid(N_ / QT, B_ * H_);
    hept_attn_kernel<<<grid, 256, 0, stream>>>(Q, K, V, maskf, idx, cnt, (float*)d_out);
}

// Round 4
// 175.850 us; speedup vs baseline: 2.2508x; 2.2508x over previous
//
#include <hip/hip_runtime.h>

typedef short short8_t __attribute__((ext_vector_type(8)));
typedef float floatx16 __attribute__((ext_vector_type(16)));

#define H_ 8
#define B_ 4
#define N_ 2048
#define D_ 64
#define EPS_ 0.0009765625f

// ---- ws layout (bytes) ----
#define MASKF_OFF 0                      // 8192 f32
#define CNT_OFF   32768                  // 4 int
#define IDX_OFF   33024                  // 8192 int
#define KHI_OFF   65536                  // [32][2048][64] bf16 = 8MB
#define KLO_OFF   (KHI_OFF + 8388608)
#define VT_OFF    (KLO_OFF + 8388608)    // [32][64][2048] bf16 = 8MB
#define K2_OFF    (VT_OFF + 8388608)     // [32][2048] f32 (-0.5*k2)
#define WS_NEED   ((size_t)(K2_OFF + 262144))

__device__ __forceinline__ unsigned short f2bf(float x) {  // RNE, finite inputs
    unsigned int u = __float_as_uint(x);
    return (unsigned short)((u + 0x7FFFu + ((u >> 16) & 1u)) >> 16);
}

// ---------------------------------------------------------------------------
// Mask canonicalization (bool buffer may be u8 / i32 / f32)
// ---------------------------------------------------------------------------
__global__ __launch_bounds__(256) void prep_mask_kernel(const void* __restrict__ min_,
                                                        float* __restrict__ mout, int n) {
    __shared__ int okInt, okFloat;
    const int t = threadIdx.x;
    if (t == 0) { okInt = 1; okFloat = 1; }
    __syncthreads();
    const unsigned int* w = (const unsigned int*)min_;
    const int nw = n / 4;
    int badI = 0, badF = 0;
    for (int i = t; i < nw; i += 256) {
        const unsigned int x = w[i];
        if (x > 1u) badI = 1;
        if (x != 0u && x != 0x3F800000u) badF = 1;
    }
    if (badI) atomicAnd(&okInt, 0);
    if (badF) atomicAnd(&okFloat, 0);
    __syncthreads();
    if (okInt) {
        const int* p = (const int*)min_;
        for (int i = t; i < n; i += 256) mout[i] = p[i] ? 1.0f : 0.0f;
    } else if (okFloat) {
        const float* p = (const float*)min_;
        for (int i = t; i < n; i += 256) mout[i] = (p[i] != 0.0f) ? 1.0f : 0.0f;
    } else {
        const unsigned char* p = (const unsigned char*)min_;
        for (int i = t; i < n; i += 256) mout[i] = p[i] ? 1.0f : 0.0f;
    }
}

// ---------------------------------------------------------------------------
// Ordered compaction of unmasked key indices per batch (deterministic)
// ---------------------------------------------------------------------------
__global__ __launch_bounds__(256) void compact_kernel(const float* __restrict__ maskf,
                                                      int* __restrict__ idx,
                                                      int* __restrict__ cnt) {
    const int b = blockIdx.x;
    const int t = threadIdx.x;
    __shared__ int pre[257];
    const float* m = maskf + b * N_;
    int loc[8];
    int c = 0;
#pragma unroll
    for (int i = 0; i < 8; ++i) {
        loc[i] = (m[t * 8 + i] != 0.0f) ? 1 : 0;
        c += loc[i];
    }
    pre[t + 1] = c;
    __syncthreads();
    if (t == 0) {
        pre[0] = 0;
        for (int i = 1; i <= 256; ++i) pre[i] += pre[i - 1];
        cnt[b] = pre[256];
    }
    __syncthreads();
    int base = pre[t];
    int* ob = idx + b * N_;
#pragma unroll
    for (int i = 0; i < 8; ++i)
        if (loc[i]) ob[base++] = t * 8 + i;
}

// ---------------------------------------------------------------------------
// Convert compacted K -> bf16 hi/lo (row-major), V -> bf16 V^T, k2 -> -0.5*k2.
// Grid: (32 row-tiles of 64, 32 planes). plane p: head=p>>2, b=p&3.
// ---------------------------------------------------------------------------
__global__ __launch_bounds__(256) void convert_kernel(
    const float* __restrict__ Kg, const float* __restrict__ Vg,
    unsigned char* __restrict__ ws) {
    const int p = blockIdx.y;
    const int head = p >> 2, b = p & 3;
    const int j0 = blockIdx.x * 64;
    const int t = threadIdx.x;
    const int jl = t >> 2, c = t & 3;
    const int j = j0 + jl;
    const int kcnt = ((const int*)(ws + CNT_OFF))[b];
    const int* idxb = (const int*)(ws + IDX_OFF) + b * N_;
    const size_t plane_f = (size_t)head * ((size_t)B_ * N_ * D_) + (size_t)b * (N_ * D_);
    __shared__ unsigned short Vb[64][64];

    float kv[16], vv[16];
    if (j < kcnt) {
        const int ki = idxb[j];
        const float4* kr = (const float4*)(Kg + plane_f + (size_t)ki * D_ + 16 * c);
        const float4* vr = (const float4*)(Vg + plane_f + (size_t)ki * D_ + 16 * c);
#pragma unroll
        for (int i = 0; i < 4; ++i) {
            float4 a = kr[i]; float4 v = vr[i];
            kv[4*i] = a.x; kv[4*i+1] = a.y; kv[4*i+2] = a.z; kv[4*i+3] = a.w;
            vv[4*i] = v.x; vv[4*i+1] = v.y; vv[4*i+2] = v.z; vv[4*i+3] = v.w;
        }
    } else {
#pragma unroll
        for (int i = 0; i < 16; ++i) { kv[i] = 0.f; vv[i] = 0.f; }
    }
    float k2 = 0.f;
    unsigned int khi[8], klo[8];
#pragma unroll
    for (int i = 0; i < 8; ++i) {
        float a0 = kv[2*i], a1 = kv[2*i+1];
        k2 = fmaf(a0, a0, k2); k2 = fmaf(a1, a1, k2);
        unsigned short h0 = f2bf(a0), h1 = f2bf(a1);
        float r0 = a0 - __uint_as_float((unsigned int)h0 << 16);
        float r1 = a1 - __uint_as_float((unsigned int)h1 << 16);
        khi[i] = (unsigned int)h0 | ((unsigned int)h1 << 16);
        klo[i] = (unsigned int)f2bf(r0) | ((unsigned int)f2bf(r1) << 16);
    }
    k2 += __shfl_xor(k2, 1);
    k2 += __shfl_xor(k2, 2);
    {
        unsigned char* dh = ws + KHI_OFF + ((size_t)p * N_ + j) * 128 + 32 * c;
        unsigned char* dl = ws + KLO_OFF + ((size_t)p * N_ + j) * 128 + 32 * c;
        ((uint4*)dh)[0] = make_uint4(khi[0], khi[1], khi[2], khi[3]);
        ((uint4*)dh)[1] = make_uint4(khi[4], khi[5], khi[6], khi[7]);
        ((uint4*)dl)[0] = make_uint4(klo[0], klo[1], klo[2], klo[3]);
        ((uint4*)dl)[1] = make_uint4(klo[4], klo[5], klo[6], klo[7]);
        if (c == 0) ((float*)(ws + K2_OFF))[(size_t)p * N_ + j] = -0.5f * k2;
    }
#pragma unroll
    for (int i = 0; i < 16; ++i) Vb[jl][16 * c + i] = f2bf(vv[i]);
    __syncthreads();
    {   // transposed write: VT row d = jl, cols j0+16c..+15
        unsigned int wds[8];
#pragma unroll
        for (int i = 0; i < 8; ++i)
            wds[i] = (unsigned int)Vb[16*c + 2*i][jl] | ((unsigned int)Vb[16*c + 2*i + 1][jl] << 16);
        unsigned char* dv = ws + VT_OFF + ((size_t)p * 64 + jl) * ((size_t)N_ * 2) + (size_t)(j0 + 16 * c) * 2;
        ((uint4*)dv)[0] = make_uint4(wds[0], wds[1], wds[2], wds[3]);
        ((uint4*)dv)[1] = make_uint4(wds[4], wds[5], wds[6], wds[7]);
    }
}

// ---------------------------------------------------------------------------
// MFMA attention: 4 waves = 2x2 (q-half, key/d-half) 32x32 quadrants.
// QK^T: split-bf16 (3x mfma_f32_32x32x16_bf16); PV: single bf16 via W in LDS.
// All LDS tiles 64x64 bf16, 16B-slot XOR swizzle (slot ^= row&7).
// C/D layout (m74/m101): col=lane&31, row=(reg&3)+8*(reg>>2)+4*(lane>>5).
// ---------------------------------------------------------------------------
__global__ __launch_bounds__(256, 3) void hept_mfma_kernel(
    const float* __restrict__ Qg, const unsigned char* __restrict__ ws,
    float* __restrict__ Out) {
    __shared__ __align__(16) unsigned short Qhi[4096], Qlo[4096], Khi[4096],
                                            Klo[4096], Vt[4096], Wt[4096];
    __shared__ float q2s[64], k2t[64], qm[64], dpart[2][64];

    const int t = threadIdx.x;
    const int l = t & 63;
    const int w = t >> 6;
    const int qh = w >> 1, kh = w & 1;

    // XCD swizzle: 32 consecutive logical tiles (one plane) per XCD
    const int cid = blockIdx.x;
    const int swz = (cid & 7) * 128 + (cid >> 3);
    const int p = swz >> 5;
    const int qb = swz & 31;
    const int head = p >> 2, b = p & 3;
    const int q0 = qb * 64;

    const size_t plane_f = (size_t)head * ((size_t)B_ * N_ * D_) + (size_t)b * (N_ * D_);
    const float* maskf = (const float*)(ws + MASKF_OFF) + b * N_;
    const int kcnt = ((const int*)(ws + CNT_OFF))[b];
    const int ntile = (kcnt + 63) >> 6;
    const unsigned short* khi_g = (const unsigned short*)(ws + KHI_OFF) + (size_t)p * ((size_t)N_ * 64);
    const unsigned short* klo_g = (const unsigned short*)(ws + KLO_OFF) + (size_t)p * ((size_t)N_ * 64);
    const unsigned short* vt_g  = (const unsigned short*)(ws + VT_OFF)  + (size_t)p * ((size_t)64 * N_);
    const float* k2_g = (const float*)(ws + K2_OFF) + (size_t)p * N_;

    // ---- prologue: stage Q hi/lo (swizzled), q2, qm ----
    {
        const int row = t >> 2, c = t & 3;
        const float4* qr = (const float4*)(Qg + plane_f + (size_t)(q0 + row) * D_ + 16 * c);
        float q[16];
#pragma unroll
        for (int i = 0; i < 4; ++i) {
            float4 a = qr[i];
            q[4*i] = a.x; q[4*i+1] = a.y; q[4*i+2] = a.z; q[4*i+3] = a.w;
        }
        float q2 = 0.f;
        unsigned int hi[8], lo[8];
#pragma unroll
        for (int i = 0; i < 8; ++i) {
            float a0 = q[2*i], a1 = q[2*i+1];
            q2 = fmaf(a0, a0, q2); q2 = fmaf(a1, a1, q2);
            unsigned short h0 = f2bf(a0), h1 = f2bf(a1);
            float r0 = a0 - __uint_as_float((unsigned int)h0 << 16);
            float r1 = a1 - __uint_as_float((unsigned int)h1 << 16);
            hi[i] = (unsigned int)h0 | ((unsigned int)h1 << 16);
            lo[i] = (unsigned int)f2bf(r0) | ((unsigned int)f2bf(r1) << 16);
        }
        q2 += __shfl_xor(q2, 1);
        q2 += __shfl_xor(q2, 2);
        if (c == 0) q2s[row] = -0.5f * q2;
        const int s0 = (2 * c) ^ (row & 7);
        const int s1 = (2 * c + 1) ^ (row & 7);
        *(uint4*)&Qhi[row * 64 + 8 * s0] = make_uint4(hi[0], hi[1], hi[2], hi[3]);
        *(uint4*)&Qhi[row * 64 + 8 * s1] = make_uint4(hi[4], hi[5], hi[6], hi[7]);
        *(uint4*)&Qlo[row * 64 + 8 * s0] = make_uint4(lo[0], lo[1], lo[2], lo[3]);
        *(uint4*)&Qlo[row * 64 + 8 * s1] = make_uint4(lo[4], lo[5], lo[6], lo[7]);
        if (t < 64) qm[t] = maskf[q0 + t];
    }
    __syncthreads();

    // per-lane frag offsets (ushort index); identical pattern for A and B sides
    const int rowA = 32 * qh + (l & 31);
    const int rowB = 32 * kh + (l & 31);
    const int g = l >> 5;
    int offA[4], offB[4];
#pragma unroll
    for (int ks = 0; ks < 4; ++ks) {
        offA[ks] = rowA * 64 + 8 * ((2 * ks + g) ^ (rowA & 7));
        offB[ks] = rowB * 64 + 8 * ((2 * ks + g) ^ (rowB & 7));
    }
    float q2r[16];
#pragma unroll
    for (int r = 0; r < 16; ++r)
        q2r[r] = q2s[32 * qh + (r & 3) + 8 * (r >> 2) + 4 * g];

    // staging: wave w covers 1KB chunks {2w, 2w+1}; lane: 16B, pre-swizzled src
    const int rch = l >> 3;
    const int sl8 = (l & 7) ^ rch;
    const int ch0 = 2 * w, ch1 = 2 * w + 1;
    const unsigned short* srcK0 = khi_g + (size_t)(ch0 * 8 + rch) * 64 + 8 * sl8;
    const unsigned short* srcK1 = khi_g + (size_t)(ch1 * 8 + rch) * 64 + 8 * sl8;
    const unsigned short* srcL0 = klo_g + (size_t)(ch0 * 8 + rch) * 64 + 8 * sl8;
    const unsigned short* srcL1 = klo_g + (size_t)(ch1 * 8 + rch) * 64 + 8 * sl8;
    const unsigned short* srcV0 = vt_g + (size_t)(ch0 * 8 + rch) * N_ + 8 * sl8;
    const unsigned short* srcV1 = vt_g + (size_t)(ch1 * 8 + rch) * N_ + 8 * sl8;
    const int dstA = ch0 * 512 + 8 * l;
    const int dstB = ch1 * 512 + 8 * l;

    floatx16 oacc;
    float dsum[16];
#pragma unroll
    for (int r = 0; r < 16; ++r) { oacc[r] = 0.f; dsum[r] = 0.f; }
    const int keycol = 32 * kh + (l & 31);

    for (int kt = 0; kt < ntile; ++kt) {
        {   // ---- stage K hi/lo + V^T tile (reg round-trip) ----
            const size_t o = (size_t)kt * (64 * 64);
            const size_t ov = (size_t)kt * 64;
            uint4 a0 = *(const uint4*)(srcK0 + o);
            uint4 a1 = *(const uint4*)(srcK1 + o);
            uint4 b0 = *(const uint4*)(srcL0 + o);
            uint4 b1 = *(const uint4*)(srcL1 + o);
            uint4 c0 = *(const uint4*)(srcV0 + ov);
            uint4 c1 = *(const uint4*)(srcV1 + ov);
            *(uint4*)&Khi[dstA] = a0;  *(uint4*)&Khi[dstB] = a1;
            *(uint4*)&Klo[dstA] = b0;  *(uint4*)&Klo[dstB] = b1;
            *(uint4*)&Vt[dstA]  = c0;  *(uint4*)&Vt[dstB]  = c1;
            if (t < 64) k2t[t] = k2_g[kt * 64 + t];
        }
        __syncthreads();

        // ---- QK^T: split bf16, 3 passes ----
        floatx16 acc;
#pragma unroll
        for (int r = 0; r < 16; ++r) acc[r] = 0.f;
#pragma unroll
        for (int ks = 0; ks < 4; ++ks) {
            short8_t qH = *(const short8_t*)&Qhi[offA[ks]];
            short8_t qL = *(const short8_t*)&Qlo[offA[ks]];
            short8_t kH = *(const short8_t*)&Khi[offB[ks]];
            short8_t kL = *(const short8_t*)&Klo[offB[ks]];
            acc = __builtin_amdgcn_mfma_f32_32x32x16_bf16(qH, kH, acc, 0, 0, 0);
            acc = __builtin_amdgcn_mfma_f32_32x32x16_bf16(qH, kL, acc, 0, 0, 0);
            acc = __builtin_amdgcn_mfma_f32_32x32x16_bf16(qL, kH, acc, 0, 0, 0);
        }

        // ---- w = exp(dot - (q2+k2)/2)*valid; fp32 denom; W tile (bf16) ----
        const float k2v = k2t[keycol];
        const float valid = (kt * 64 + keycol < kcnt) ? 1.f : 0.f;
        const int slotbase = keycol >> 3;
        const int crem = keycol & 7;
#pragma unroll
        for (int r = 0; r < 16; ++r) {
            float wv = __expf(acc[r] + q2r[r] + k2v) * valid;
            dsum[r] += wv;
            const int rowW = 32 * qh + (r & 3) + 8 * (r >> 2) + 4 * g;
            Wt[rowW * 64 + 8 * (slotbase ^ (rowW & 7)) + crem] = f2bf(wv);
        }
        __syncthreads();

        // ---- PV: O[q][d] += W[q][k] * V[k][d] ----
#pragma unroll
        for (int ks = 0; ks < 4; ++ks) {
            short8_t aW = *(const short8_t*)&Wt[offA[ks]];
            short8_t bV = *(const short8_t*)&Vt[offB[ks]];
            oacc = __builtin_amdgcn_mfma_f32_32x32x16_bf16(aW, bV, oacc, 0, 0, 0);
        }
        __syncthreads();
    }

    // ---- epilogue: denom reduce + normalize + store ----
#pragma unroll
    for (int r = 0; r < 16; ++r) {
        float s = dsum[r];
        s += __shfl_xor(s, 1); s += __shfl_xor(s, 2); s += __shfl_xor(s, 4);
        s += __shfl_xor(s, 8); s += __shfl_xor(s, 16);
        dsum[r] = s;
    }
    if ((l & 31) == 0) {
#pragma unroll
        for (int r = 0; r < 16; ++r)
            dpart[kh][32 * qh + (r & 3) + 8 * (r >> 2) + 4 * g] = dsum[r];
    }
    __syncthreads();
    float* Op = Out + plane_f + (size_t)q0 * D_;
#pragma unroll
    for (int r = 0; r < 16; ++r) {
        const int rowq = 32 * qh + (r & 3) + 8 * (r >> 2) + 4 * g;
        const float den = EPS_ + dpart[0][rowq] + dpart[1][rowq];
        const float inv = qm[rowq] / den;
        Op[(size_t)rowq * D_ + keycol] = oacc[r] * inv;
    }
}

// ---------------------------------------------------------------------------
// fp32 fallback (round-3 kernel, used only if ws_size < WS_NEED)
// ---------------------------------------------------------------------------
__global__ __launch_bounds__(256) void hept_attn_fp32(
    const float* __restrict__ Q, const float* __restrict__ K,
    const float* __restrict__ V, const float* __restrict__ maskf,
    const int* __restrict__ idx, const int* __restrict__ cnt,
    float* __restrict__ Out) {
    __shared__ float Qs[64 * 64];
    __shared__ float KWs[64 * 64];
    __shared__ float Vs[64 * 64];
    __shared__ float q2s[64];
    __shared__ float k2s[64];
    __shared__ float mks[64];

    const int t = threadIdx.x;
    const int tr = t >> 4, tc = t & 15;
    const int q0 = blockIdx.x * 64;
    const int head = blockIdx.y & 7;
    const int b = blockIdx.y >> 3;

    const size_t plane = (size_t)(B_ * N_) * D_;
    const float* Qp = Q + (size_t)head * plane + (size_t)(b * N_ + q0) * D_;
    const float* Kp = K + (size_t)head * plane + (size_t)(b * N_) * D_;
    const float* Vp = V + (size_t)head * plane + (size_t)(b * N_) * D_;
    float* Op = Out + (size_t)head * plane + (size_t)(b * N_ + q0) * D_;
    const float* mrow = maskf + b * N_;
    const int* idxb = idx + b * N_;
    const int kcnt = cnt[b];
    const int ntile = (kcnt + 63) / 64;

    for (int f = t; f < 64 * 64 / 4; f += 256) {
        const int r = f >> 4, c4 = f & 15;
        const float4 v = *(const float4*)(Qp + r * 64 + (c4 << 2));
        const int cs = c4 ^ ((r >> 2) & 7);
        *(float4*)&Qs[r * 64 + (cs << 2)] = v;
    }
    __syncthreads();
    if (t < 64) {
        float s = 0.f;
        const int sw = (t >> 2) & 7;
#pragma unroll
        for (int i4 = 0; i4 < 16; ++i4) {
            const float4 v = *(const float4*)&Qs[t * 64 + ((i4 ^ sw) << 2)];
            s = fmaf(v.x, v.x, s); s = fmaf(v.y, v.y, s);
            s = fmaf(v.z, v.z, s); s = fmaf(v.w, v.w, s);
        }
        q2s[t] = s;
    }
    float4 accO[4];
#pragma unroll
    for (int a = 0; a < 4; ++a) accO[a] = make_float4(0.f, 0.f, 0.f, 0.f);
    float dsum[4] = {0.f, 0.f, 0.f, 0.f};
    const int swA = tr & 7, swB = tc & 7;

    for (int kt = 0; kt < ntile; ++kt) {
        const int k0 = kt * 64;
        __syncthreads();
        for (int f = t; f < 64 * 64 / 4; f += 256) {
            const int r = f >> 4, c4 = f & 15;
            const int j = k0 + r;
            const int ki = (j < kcnt) ? idxb[j] : idxb[0];
            const int cs = c4 ^ ((r >> 2) & 7);
            *(float4*)&KWs[r * 64 + (cs << 2)] = *(const float4*)(Kp + (size_t)ki * 64 + (c4 << 2));
            *(float4*)&Vs[r * 64 + (cs << 2)]  = *(const float4*)(Vp + (size_t)ki * 64 + (c4 << 2));
        }
        if (t < 64) mks[t] = (k0 + t < kcnt) ? 1.0f : 0.0f;
        __syncthreads();
        if (t < 64) {
            float s = 0.f;
            const int sw = (t >> 2) & 7;
#pragma unroll
            for (int i4 = 0; i4 < 16; ++i4) {
                const float4 v = *(const float4*)&KWs[t * 64 + ((i4 ^ sw) << 2)];
                s = fmaf(v.x, v.x, s); s = fmaf(v.y, v.y, s);
                s = fmaf(v.z, v.z, s); s = fmaf(v.w, v.w, s);
            }
            k2s[t] = s;
        }
        float dot[4][4];
#pragma unroll
        for (int a = 0; a < 4; ++a)
#pragma unroll
            for (int c = 0; c < 4; ++c) dot[a][c] = 0.f;
#pragma unroll
        for (int i4 = 0; i4 < 16; ++i4) {
            float4 qv[4], kv[4];
            const int qc = (i4 ^ swA) << 2;
            const int kc = (i4 ^ swB) << 2;
#pragma unroll
            for (int a = 0; a < 4; ++a) qv[a] = *(const float4*)&Qs[(4 * tr + a) * 64 + qc];
#pragma unroll
            for (int c = 0; c < 4; ++c) kv[c] = *(const float4*)&KWs[(4 * tc + c) * 64 + kc];
#pragma unroll
            for (int a = 0; a < 4; ++a)
#pragma unroll
                for (int c = 0; c < 4; ++c) {
                    dot[a][c] = fmaf(qv[a].x, kv[c].x, dot[a][c]);
                    dot[a][c] = fmaf(qv[a].y, kv[c].y, dot[a][c]);
                    dot[a][c] = fmaf(qv[a].z, kv[c].z, dot[a][c]);
                    dot[a][c] = fmaf(qv[a].w, kv[c].w, dot[a][c]);
                }
        }
        __syncthreads();
        float4 wrow[4];
#pragma unroll
        for (int a = 0; a < 4; ++a) {
            const float q2 = q2s[4 * tr + a];
            const float w0 = __expf(-0.5f * (q2 + k2s[4 * tc + 0] - 2.f * dot[a][0])) * mks[4 * tc + 0];
            const float w1 = __expf(-0.5f * (q2 + k2s[4 * tc + 1] - 2.f * dot[a][1])) * mks[4 * tc + 1];
            const float w2 = __expf(-0.5f * (q2 + k2s[4 * tc + 2] - 2.f * dot[a][2])) * mks[4 * tc + 2];
            const float w3 = __expf(-0.5f * (q2 + k2s[4 * tc + 3] - 2.f * dot[a][3])) * mks[4 * tc + 3];
            dsum[a] += (w0 + w1) + (w2 + w3);
            wrow[a] = make_float4(w0, w1, w2, w3);
        }
#pragma unroll
        for (int a = 0; a < 4; ++a)
            *(float4*)&KWs[(4 * tr + a) * 64 + ((tc ^ swA) << 2)] = wrow[a];
        __syncthreads();
#pragma unroll
        for (int k4 = 0; k4 < 16; ++k4) {
            float4 wv[4], vv[4];
            const int wc = (k4 ^ swA) << 2;
            const int vc = (tc ^ (k4 & 7)) << 2;
#pragma unroll
            for (int a = 0; a < 4; ++a) wv[a] = *(const float4*)&KWs[(4 * tr + a) * 64 + wc];
#pragma unroll
            for (int c = 0; c < 4; ++c) vv[c] = *(const float4*)&Vs[(4 * k4 + c) * 64 + vc];
#pragma unroll
            for (int a = 0; a < 4; ++a) {
                accO[a].x = fmaf(wv[a].x, vv[0].x, accO[a].x);
                accO[a].x = fmaf(wv[a].y, vv[1].x, accO[a].x);
                accO[a].x = fmaf(wv[a].z, vv[2].x, accO[a].x);
                accO[a].x = fmaf(wv[a].w, vv[3].x, accO[a].x);
                accO[a].y = fmaf(wv[a].x, vv[0].y, accO[a].y);
                accO[a].y = fmaf(wv[a].y, vv[1].y, accO[a].y);
                accO[a].y = fmaf(wv[a].z, vv[2].y, accO[a].y);
                accO[a].y = fmaf(wv[a].w, vv[3].y, accO[a].y);
                accO[a].z = fmaf(wv[a].x, vv[0].z, accO[a].z);
                accO[a].z = fmaf(wv[a].y, vv[1].z, accO[a].z);
                accO[a].z = fmaf(wv[a].z, vv[2].z, accO[a].z);
                accO[a].z = fmaf(wv[a].w, vv[3].z, accO[a].z);
                accO[a].w = fmaf(wv[a].x, vv[0].w, accO[a].w);
                accO[a].w = fmaf(wv[a].y, vv[1].w, accO[a].w);
                accO[a].w = fmaf(wv[a].z, vv[2].w, accO[a].w);
                accO[a].w = fmaf(wv[a].w, vv[3].w, accO[a].w);
            }
        }
    }
    __syncthreads();
    float* dpart2 = Vs;
#pragma unroll
    for (int a = 0; a < 4; ++a) dpart2[tc * 64 + 4 * tr + a] = dsum[a];
    __syncthreads();
#pragma unroll
    for (int a = 0; a < 4; ++a) {
        const int r = 4 * tr + a;
        float den = EPS_;
#pragma unroll
        for (int j = 0; j < 16; ++j) den += dpart2[j * 64 + r];
        const float mq = mrow[q0 + r];
        const float inv = mq / den;
        const float4 o = make_float4(accO[a].x * inv, accO[a].y * inv,
                                     accO[a].z * inv, accO[a].w * inv);
        *(float4*)(Op + (size_t)r * 64 + (tc << 2)) = o;
    }
}

extern "C" void kernel_launch(void* const* d_in, const int* in_sizes, int n_in,
                              void* d_out, int out_size, void* d_ws, size_t ws_size,
                              hipStream_t stream) {
    (void)n_in; (void)out_size;
    const float* Q = (const float*)d_in[0];
    const float* K = (const float*)d_in[1];
    const float* V = (const float*)d_in[2];
    const void* mask = d_in[3];
    unsigned char* wsb = (unsigned char*)d_ws;

    prep_mask_kernel<<<1, 256, 0, stream>>>(mask, (float*)(wsb + MASKF_OFF), in_sizes[3]);
    compact_kernel<<<B_, 256, 0, stream>>>((const float*)(wsb + MASKF_OFF),
                                           (int*)(wsb + IDX_OFF), (int*)(wsb + CNT_OFF));
    if (ws_size >= WS_NEED) {
        dim3 cg(N_ / 64, 32);
        convert_kernel<<<cg, 256, 0, stream>>>(K, V, wsb);
        hept_mfma_kernel<<<1024, 256, 0, stream>>>(Q, wsb, (float*)d_out);
    } else {
        dim3 grid(N_ / 64, B_ * H_);
        hept_attn_fp32<<<grid, 256, 0, stream>>>(Q, K, V, (const float*)(wsb + MASKF_OFF),
                                                 (const int*)(wsb + IDX_OFF),
                                                 (const int*)(wsb + CNT_OFF), (float*)d_out);
    }
}

// Round 8
// 151.283 us; speedup vs baseline: 2.6163x; 1.1624x over previous
//
#include <hip/hip_runtime.h>

typedef short short8_t __attribute__((ext_vector_type(8)));
typedef float floatx16 __attribute__((ext_vector_type(16)));

#define H_ 8
#define B_ 4
#define N_ 2048
#define D_ 64
#define EPS_ 0.0009765625f

// ---- ws layout (bytes) ----
#define CNT_OFF   0                      // 4 int
#define IDX_OFF   256                    // [4][2048] int: unmasked indices
#define ZIDX_OFF  33024                  // [4][2048] int: masked indices
#define KHI_OFF   65792                  // [32][2048][64] bf16 = 8MB
#define KLO_OFF   (KHI_OFF + 8388608)
#define VT_OFF    (KLO_OFF + 8388608)    // [32][64][2048] bf16 = 8MB
#define K2_OFF    (VT_OFF + 8388608)     // [32][2048] f32 (-0.5*k2)
#define WS_NEED   ((size_t)(K2_OFF + 262144))

__device__ __forceinline__ unsigned short f2bf(float x) {  // RNE, finite inputs
    unsigned int u = __float_as_uint(x);
    return (unsigned short)((u + 0x7FFFu + ((u >> 16) & 1u)) >> 16);
}

// ---------------------------------------------------------------------------
// Fused mask-format detection + per-batch ordered compaction (4 blocks).
// Detection reads words [0,512) — valid under u8/i32/f32 layouts; random 0/1
// data discriminates with overwhelming probability.
// ---------------------------------------------------------------------------
__global__ __launch_bounds__(256) void prep_kernel(const void* __restrict__ mask,
                                                   unsigned char* __restrict__ ws) {
    __shared__ int okInt, okFloat;
    __shared__ int pre[257], zpre[257];
    const int t = threadIdx.x, b = blockIdx.x;
    if (t == 0) { okInt = 1; okFloat = 1; }
    __syncthreads();
    const unsigned int* w = (const unsigned int*)mask;
    int badI = 0, badF = 0;
    for (int i = t; i < 512; i += 256) {
        const unsigned int x = w[i];
        if (x > 1u) badI = 1;
        if (x != 0u && x != 0x3F800000u) badF = 1;
    }
    if (badI) atomicAnd(&okInt, 0);
    if (badF) atomicAnd(&okFloat, 0);
    __syncthreads();
    int loc[8];
    const int e0 = b * N_ + t * 8;
    if (okInt) {
        const int* p = (const int*)mask;
#pragma unroll
        for (int i = 0; i < 8; ++i) loc[i] = (p[e0 + i] != 0) ? 1 : 0;
    } else if (okFloat) {
        const float* p = (const float*)mask;
#pragma unroll
        for (int i = 0; i < 8; ++i) loc[i] = (p[e0 + i] != 0.0f) ? 1 : 0;
    } else {
        const unsigned char* p = (const unsigned char*)mask;
#pragma unroll
        for (int i = 0; i < 8; ++i) loc[i] = p[e0 + i] ? 1 : 0;
    }
    int c = 0;
#pragma unroll
    for (int i = 0; i < 8; ++i) c += loc[i];
    pre[t + 1] = c;
    zpre[t + 1] = 8 - c;
    __syncthreads();
    if (t == 0) {
        pre[0] = 0; zpre[0] = 0;
        for (int i = 1; i <= 256; ++i) { pre[i] += pre[i - 1]; zpre[i] += zpre[i - 1]; }
        ((int*)(ws + CNT_OFF))[b] = pre[256];
    }
    __syncthreads();
    int* ob = (int*)(ws + IDX_OFF) + b * N_;
    int* zb = (int*)(ws + ZIDX_OFF) + b * N_;
    int u = pre[t], z = zpre[t];
#pragma unroll
    for (int i = 0; i < 8; ++i) {
        if (loc[i]) ob[u++] = t * 8 + i;
        else        zb[z++] = t * 8 + i;
    }
}

// ---------------------------------------------------------------------------
// Zero-fill masked output rows (poisoned buffer must be written explicitly).
// Grid: 128 blocks = 32 planes x 4 parts.
// ---------------------------------------------------------------------------
__global__ __launch_bounds__(256) void zero_kernel(const unsigned char* __restrict__ ws,
                                                   float* __restrict__ Out) {
    const int p = blockIdx.x >> 2;
    const int part = blockIdx.x & 3;
    const int head = p >> 2, b = p & 3;
    const int zcnt = N_ - ((const int*)(ws + CNT_OFF))[b];
    const int* zb = (const int*)(ws + ZIDX_OFF) + b * N_;
    const size_t plane_f = (size_t)head * ((size_t)B_ * N_ * D_) + (size_t)b * (N_ * D_);
    const float4 z4 = make_float4(0.f, 0.f, 0.f, 0.f);
    for (int i = part * 256 + threadIdx.x; i < zcnt * 16; i += 1024) {
        const int row = zb[i >> 4];
        const int c = i & 15;
        *(float4*)(Out + plane_f + (size_t)row * D_ + 4 * c) = z4;
    }
}

// ---------------------------------------------------------------------------
// Convert compacted K -> bf16 hi/lo (row-major), V -> bf16 V^T, k2 -> -0.5*k2.
// Grid: (32 row-tiles of 64, 32 planes); early-exit for tiles >= kcnt.
// Vb padded to [64][66] (33-dword rows, gcd(33,32)=1) to kill transpose
// bank conflicts.
// ---------------------------------------------------------------------------
__global__ __launch_bounds__(256) void convert_kernel(
    const float* __restrict__ Kg, const float* __restrict__ Vg,
    unsigned char* __restrict__ ws) {
    const int p = blockIdx.y;
    const int head = p >> 2, b = p & 3;
    const int j0 = blockIdx.x * 64;
    const int kcnt = ((const int*)(ws + CNT_OFF))[b];
    if (j0 >= kcnt) return;  // uniform exit: tile never read
    const int t = threadIdx.x;
    const int jl = t >> 2, c = t & 3;
    const int j = j0 + jl;
    const int* idxb = (const int*)(ws + IDX_OFF) + b * N_;
    const size_t plane_f = (size_t)head * ((size_t)B_ * N_ * D_) + (size_t)b * (N_ * D_);
    __shared__ unsigned short Vb[64][66];

    float kv[16], vv[16];
    if (j < kcnt) {
        const int ki = idxb[j];
        const float4* kr = (const float4*)(Kg + plane_f + (size_t)ki * D_ + 16 * c);
        const float4* vr = (const float4*)(Vg + plane_f + (size_t)ki * D_ + 16 * c);
#pragma unroll
        for (int i = 0; i < 4; ++i) {
            float4 a = kr[i]; float4 v = vr[i];
            kv[4*i] = a.x; kv[4*i+1] = a.y; kv[4*i+2] = a.z; kv[4*i+3] = a.w;
            vv[4*i] = v.x; vv[4*i+1] = v.y; vv[4*i+2] = v.z; vv[4*i+3] = v.w;
        }
    } else {
#pragma unroll
        for (int i = 0; i < 16; ++i) { kv[i] = 0.f; vv[i] = 0.f; }
    }
    float k2 = 0.f;
    unsigned int khi[8], klo[8];
#pragma unroll
    for (int i = 0; i < 8; ++i) {
        float a0 = kv[2*i], a1 = kv[2*i+1];
        k2 = fmaf(a0, a0, k2); k2 = fmaf(a1, a1, k2);
        unsigned short h0 = f2bf(a0), h1 = f2bf(a1);
        float r0 = a0 - __uint_as_float((unsigned int)h0 << 16);
        float r1 = a1 - __uint_as_float((unsigned int)h1 << 16);
        khi[i] = (unsigned int)h0 | ((unsigned int)h1 << 16);
        klo[i] = (unsigned int)f2bf(r0) | ((unsigned int)f2bf(r1) << 16);
    }
    k2 += __shfl_xor(k2, 1);
    k2 += __shfl_xor(k2, 2);
    {
        unsigned char* dh = ws + KHI_OFF + ((size_t)p * N_ + j) * 128 + 32 * c;
        unsigned char* dl = ws + KLO_OFF + ((size_t)p * N_ + j) * 128 + 32 * c;
        ((uint4*)dh)[0] = make_uint4(khi[0], khi[1], khi[2], khi[3]);
        ((uint4*)dh)[1] = make_uint4(khi[4], khi[5], khi[6], khi[7]);
        ((uint4*)dl)[0] = make_uint4(klo[0], klo[1], klo[2], klo[3]);
        ((uint4*)dl)[1] = make_uint4(klo[4], klo[5], klo[6], klo[7]);
        if (c == 0) ((float*)(ws + K2_OFF))[(size_t)p * N_ + j] = -0.5f * k2;
    }
#pragma unroll
    for (int i = 0; i < 16; ++i) Vb[jl][16 * c + i] = f2bf(vv[i]);
    __syncthreads();
    {   // transposed write: VT row d = jl, cols j0+16c..+15
        unsigned int wds[8];
#pragma unroll
        for (int i = 0; i < 8; ++i)
            wds[i] = (unsigned int)Vb[16*c + 2*i][jl] | ((unsigned int)Vb[16*c + 2*i + 1][jl] << 16);
        unsigned char* dv = ws + VT_OFF + ((size_t)p * 64 + jl) * ((size_t)N_ * 2) + (size_t)(j0 + 16 * c) * 2;
        ((uint4*)dv)[0] = make_uint4(wds[0], wds[1], wds[2], wds[3]);
        ((uint4*)dv)[1] = make_uint4(wds[4], wds[5], wds[6], wds[7]);
    }
}

// ---------------------------------------------------------------------------
// MFMA attention over compacted queries AND keys.
// 4 waves = 2x2 (q-half, key/d-half) 32x32 quadrants.
// QK^T: split-bf16 (3x mfma_f32_32x32x16_bf16); PV: single bf16 via W in LDS.
// Stage-ahead: next tile's global loads issue right after the staged barrier,
// hiding HBM/L2 latency under QK+exp.
// C/D layout (m74/m101): col=lane&31, row=(reg&3)+8*(reg>>2)+4*(lane>>5).
// ---------------------------------------------------------------------------
__global__ __launch_bounds__(256, 3) void hept_mfma_kernel(
    const float* __restrict__ Qg, const unsigned char* __restrict__ ws,
    float* __restrict__ Out) {
    __shared__ __align__(16) unsigned short Qhi[4096], Qlo[4096], Khi[4096],
                                            Klo[4096], Vt[4096], Wt[4096];
    __shared__ float q2s[64], k2t[64], dpart[2][64];
    __shared__ int qidx_s[64];

    const int t = threadIdx.x;
    const int l = t & 63;
    const int w = t >> 6;
    const int qh = w >> 1, kh = w & 1;

    // XCD swizzle: 4 consecutive planes per XCD (K/V slices stay L2-resident)
    const int cid = blockIdx.x;
    const int swz = (cid & 7) * 128 + (cid >> 3);
    const int p = swz >> 5;
    const int qb = swz & 31;
    const int head = p >> 2, b = p & 3;
    const int q0 = qb * 64;

    const int kcnt = ((const int*)(ws + CNT_OFF))[b];
    if (q0 >= kcnt) return;  // uniform: no compacted q rows in this tile
    const int ntile = (kcnt + 63) >> 6;
    const int* idxb = (const int*)(ws + IDX_OFF) + b * N_;

    const size_t plane_f = (size_t)head * ((size_t)B_ * N_ * D_) + (size_t)b * (N_ * D_);
    const unsigned short* khi_g = (const unsigned short*)(ws + KHI_OFF) + (size_t)p * ((size_t)N_ * 64);
    const unsigned short* klo_g = (const unsigned short*)(ws + KLO_OFF) + (size_t)p * ((size_t)N_ * 64);
    const unsigned short* vt_g  = (const unsigned short*)(ws + VT_OFF)  + (size_t)p * ((size_t)64 * N_);
    const float* k2_g = (const float*)(ws + K2_OFF) + (size_t)p * N_;

    // ---- prologue: gather+stage Q hi/lo (swizzled), q2, qidx ----
    {
        const int row = t >> 2, c = t & 3;
        const int jq = q0 + row;
        const int qi = (jq < kcnt) ? idxb[jq] : idxb[0];
        const float4* qr = (const float4*)(Qg + plane_f + (size_t)qi * D_ + 16 * c);
        float q[16];
#pragma unroll
        for (int i = 0; i < 4; ++i) {
            float4 a = qr[i];
            q[4*i] = a.x; q[4*i+1] = a.y; q[4*i+2] = a.z; q[4*i+3] = a.w;
        }
        float q2 = 0.f;
        unsigned int hi[8], lo[8];
#pragma unroll
        for (int i = 0; i < 8; ++i) {
            float a0 = q[2*i], a1 = q[2*i+1];
            q2 = fmaf(a0, a0, q2); q2 = fmaf(a1, a1, q2);
            unsigned short h0 = f2bf(a0), h1 = f2bf(a1);
            float r0 = a0 - __uint_as_float((unsigned int)h0 << 16);
            float r1 = a1 - __uint_as_float((unsigned int)h1 << 16);
            hi[i] = (unsigned int)h0 | ((unsigned int)h1 << 16);
            lo[i] = (unsigned int)f2bf(r0) | ((unsigned int)f2bf(r1) << 16);
        }
        q2 += __shfl_xor(q2, 1);
        q2 += __shfl_xor(q2, 2);
        if (c == 0) q2s[row] = -0.5f * q2;
        const int s0 = (2 * c) ^ (row & 7);
        const int s1 = (2 * c + 1) ^ (row & 7);
        *(uint4*)&Qhi[row * 64 + 8 * s0] = make_uint4(hi[0], hi[1], hi[2], hi[3]);
        *(uint4*)&Qhi[row * 64 + 8 * s1] = make_uint4(hi[4], hi[5], hi[6], hi[7]);
        *(uint4*)&Qlo[row * 64 + 8 * s0] = make_uint4(lo[0], lo[1], lo[2], lo[3]);
        *(uint4*)&Qlo[row * 64 + 8 * s1] = make_uint4(lo[4], lo[5], lo[6], lo[7]);
        if (t < 64) qidx_s[t] = (q0 + t < kcnt) ? idxb[q0 + t] : 0;
    }
    __syncthreads();

    // per-lane frag offsets (ushort index); identical pattern for A and B sides
    const int rowA = 32 * qh + (l & 31);
    const int rowB = 32 * kh + (l & 31);
    const int g = l >> 5;
    int offA[4], offB[4];
#pragma unroll
    for (int ks = 0; ks < 4; ++ks) {
        offA[ks] = rowA * 64 + 8 * ((2 * ks + g) ^ (rowA & 7));
        offB[ks] = rowB * 64 + 8 * ((2 * ks + g) ^ (rowB & 7));
    }
    float q2r[16];
#pragma unroll
    for (int r = 0; r < 16; ++r)
        q2r[r] = q2s[32 * qh + (r & 3) + 8 * (r >> 2) + 4 * g];

    // staging geometry: wave w covers 1KB chunks {2w,2w+1}; lane: 16B,
    // pre-swizzled global source so LDS dest stays linear
    const int rch = l >> 3;
    const int sl8 = (l & 7) ^ rch;
    const int ch0 = 2 * w, ch1 = 2 * w + 1;
    const unsigned short* srcK0 = khi_g + (size_t)(ch0 * 8 + rch) * 64 + 8 * sl8;
    const unsigned short* srcK1 = khi_g + (size_t)(ch1 * 8 + rch) * 64 + 8 * sl8;
    const unsigned short* srcL0 = klo_g + (size_t)(ch0 * 8 + rch) * 64 + 8 * sl8;
    const unsigned short* srcL1 = klo_g + (size_t)(ch1 * 8 + rch) * 64 + 8 * sl8;
    const unsigned short* srcV0 = vt_g + (size_t)(ch0 * 8 + rch) * N_ + 8 * sl8;
    const unsigned short* srcV1 = vt_g + (size_t)(ch1 * 8 + rch) * N_ + 8 * sl8;
    const int dstA = ch0 * 512 + 8 * l;
    const int dstB = ch1 * 512 + 8 * l;

    floatx16 oacc;
    float dsum[16];
#pragma unroll
    for (int r = 0; r < 16; ++r) { oacc[r] = 0.f; dsum[r] = 0.f; }
    const int keycol = 32 * kh + (l & 31);
    const int slotbase = keycol >> 3;
    const int crem = keycol & 7;

    uint4 rA0, rA1, rB0, rB1, rC0, rC1;
    float rk2;
#define LOADT(kt_) do { \
        const size_t o_ = (size_t)(kt_) * 4096; \
        const size_t ov_ = (size_t)(kt_) * 64; \
        rA0 = *(const uint4*)(srcK0 + o_); rA1 = *(const uint4*)(srcK1 + o_); \
        rB0 = *(const uint4*)(srcL0 + o_); rB1 = *(const uint4*)(srcL1 + o_); \
        rC0 = *(const uint4*)(srcV0 + ov_); rC1 = *(const uint4*)(srcV1 + ov_); \
        rk2 = (t < 64) ? k2_g[(kt_) * 64 + t] : 0.f; \
    } while (0)

    LOADT(0);
    for (int kt = 0; kt < ntile; ++kt) {
        __syncthreads();   // barA: prev tile's frag reads done -> LDS free
        *(uint4*)&Khi[dstA] = rA0;  *(uint4*)&Khi[dstB] = rA1;
        *(uint4*)&Klo[dstA] = rB0;  *(uint4*)&Klo[dstB] = rB1;
        *(uint4*)&Vt[dstA]  = rC0;  *(uint4*)&Vt[dstB]  = rC1;
        if (t < 64) k2t[t] = rk2;
        __syncthreads();   // barB: staged
        if (kt + 1 < ntile) LOADT(kt + 1);  // prefetch hides under QK+exp

        // ---- QK^T: split bf16, 3 passes ----
        floatx16 acc;
#pragma unroll
        for (int r = 0; r < 16; ++r) acc[r] = 0.f;
#pragma unroll
        for (int ks = 0; ks < 4; ++ks) {
            short8_t qH = *(const short8_t*)&Qhi[offA[ks]];
            short8_t qL = *(const short8_t*)&Qlo[offA[ks]];
            short8_t kH = *(const short8_t*)&Khi[offB[ks]];
            short8_t kL = *(const short8_t*)&Klo[offB[ks]];
            acc = __builtin_amdgcn_mfma_f32_32x32x16_bf16(qH, kH, acc, 0, 0, 0);
            acc = __builtin_amdgcn_mfma_f32_32x32x16_bf16(qH, kL, acc, 0, 0, 0);
            acc = __builtin_amdgcn_mfma_f32_32x32x16_bf16(qL, kH, acc, 0, 0, 0);
        }

        // ---- w = exp(dot -(q2+k2)/2)*valid; fp32 denom; W tile (bf16) ----
        const float k2v = k2t[keycol];
        const float valid = (kt * 64 + keycol < kcnt) ? 1.f : 0.f;
#pragma unroll
        for (int r = 0; r < 16; ++r) {
            float wv = __expf(acc[r] + q2r[r] + k2v) * valid;
            dsum[r] += wv;
            const int rowW = 32 * qh + (r & 3) + 8 * (r >> 2) + 4 * g;
            Wt[rowW * 64 + 8 * (slotbase ^ (rowW & 7)) + crem] = f2bf(wv);
        }
        __syncthreads();   // barC: W visible

        // ---- PV: O[q][d] += W[q][k] * V[k][d] ----
#pragma unroll
        for (int ks = 0; ks < 4; ++ks) {
            short8_t aW = *(const short8_t*)&Wt[offA[ks]];
            short8_t bV = *(const short8_t*)&Vt[offB[ks]];
            oacc = __builtin_amdgcn_mfma_f32_32x32x16_bf16(aW, bV, oacc, 0, 0, 0);
        }
    }
#undef LOADT

    // ---- epilogue: denom reduce + normalize + scatter-store ----
#pragma unroll
    for (int r = 0; r < 16; ++r) {
        float s = dsum[r];
        s += __shfl_xor(s, 1); s += __shfl_xor(s, 2); s += __shfl_xor(s, 4);
        s += __shfl_xor(s, 8); s += __shfl_xor(s, 16);
        dsum[r] = s;
    }
    __syncthreads();   // last tile's frag reads done before dpart reuse
    if ((l & 31) == 0) {
#pragma unroll
        for (int r = 0; r < 16; ++r)
            dpart[kh][32 * qh + (r & 3) + 8 * (r >> 2) + 4 * g] = dsum[r];
    }
    __syncthreads();
    float* Op = Out + plane_f;
#pragma unroll
    for (int r = 0; r < 16; ++r) {
        const int rowq = 32 * qh + (r & 3) + 8 * (r >> 2) + 4 * g;
        if (q0 + rowq < kcnt) {
            const float den = EPS_ + dpart[0][rowq] + dpart[1][rowq];
            const float inv = 1.0f / den;
            Op[(size_t)qidx_s[rowq] * D_ + keycol] = oacc[r] * inv;
        }
    }
}

extern "C" void kernel_launch(void* const* d_in, const int* in_sizes, int n_in,
                              void* d_out, int out_size, void* d_ws, size_t ws_size,
                              hipStream_t stream) {
    (void)n_in; (void)out_size; (void)in_sizes; (void)ws_size;
    const float* Q = (const float*)d_in[0];
    const float* K = (const float*)d_in[1];
    const float* V = (const float*)d_in[2];
    const void* mask = d_in[3];
    unsigned char* wsb = (unsigned char*)d_ws;

    prep_kernel<<<B_, 256, 0, stream>>>(mask, wsb);
    dim3 cg(N_ / 64, 32);
    convert_kernel<<<cg, 256, 0, stream>>>(K, V, wsb);
    zero_kernel<<<128, 256, 0, stream>>>(wsb, (float*)d_out);
    hept_mfma_kernel<<<1024, 256, 0, stream>>>(Q, wsb, (float*)d_out);
}